// Round 6
// baseline (1323.865 us; speedup 1.0000x reference)
//
#include <hip/hip_runtime.h>
#include <hip/hip_bf16.h>

#define BLK   256
#define NSAMP 558
#define NRAYS 2048
#define RESI  160
#define R2I   25600
#define R3I   4096000
#define NTOT  (NRAYS * NSAMP)          // 1,142,784
#define SAMP_BLOCKS (NTOT / BLK)       // 4464 exact
#define RAYSTRIDE 32
#define NVOX  4096000                  // 160^3
#define TG_BLOCKS (NVOX / BLK)         // 16000 exact

#define ACT_SHIFT_F (-4.5951198501345896f)
#define STEP_F 0.00625f   // STEPSIZE * VOXEL

// ---------------- ws layout ----------------
// [0]          int flag
// [256]        float rayData[2048*32]            (262,144 B)
// [SAMP_OFF]   float4 samp[NTOT]                 (18,284,544 B)
// [TG_OFF]     ushort tgrid[160^3 * 16]          (131,072,000 B)   [big paths]
// [LAT_OFF]    float4 latA/latB/latC[NTOT]       (3 x 18,284,544 B) [split path]
#define RAYDATA_OFF 256
#define SAMP_OFF    (RAYDATA_OFF + NRAYS * RAYSTRIDE * 4)
#define TG_OFF      (SAMP_OFF + (size_t)NTOT * 16)
#define WS_BIG      (TG_OFF + (size_t)NVOX * 32)
#define LAT_OFF     WS_BIG
#define WS_SPLIT    (LAT_OFF + (size_t)NTOT * 48)

template <typename T> __device__ __forceinline__ float ldv(const T* p, int i);
template <> __device__ __forceinline__ float ldv<float>(const float* p, int i) { return p[i]; }
template <> __device__ __forceinline__ float ldv<__hip_bfloat16>(const __hip_bfloat16* p, int i) {
    return __bfloat162float(p[i]);
}
template <typename T> __device__ __forceinline__ T cvt_out(float v);
template <> __device__ __forceinline__ float cvt_out<float>(float v) { return v; }
template <> __device__ __forceinline__ __hip_bfloat16 cvt_out<__hip_bfloat16>(float v) {
    return __float2bfloat16(v);
}
__device__ __forceinline__ float b2f(unsigned short u) {
    union { float f; unsigned int i; } c; c.i = ((unsigned int)u) << 16; return c.f;
}
__device__ __forceinline__ float lo16(unsigned int u) {
    union { float f; unsigned int i; } c; c.i = u << 16; return c.f;
}
__device__ __forceinline__ float hi16(unsigned int u) {
    union { float f; unsigned int i; } c; c.i = u & 0xffff0000u; return c.f;
}
__device__ __forceinline__ unsigned short f2b(float v) {
    __hip_bfloat16 h = __float2bfloat16(v);
    unsigned short u;
    __builtin_memcpy(&u, &h, sizeof(u));
    return u;
}

template <typename T>
struct KParams {
    const T *rays_o, *rays_d, *viewdirs, *grid;
    const T *aw1,*ab1,*aw2,*ab2,*aw3,*ab3;
    const T *pw1,*pb1,*pw2,*pb2,*pw3,*pb3;
    const T *dw1,*db1,*dw2,*db2,*dw3,*db3,*dw4,*db4;
    T *out;
    const int* flag;
    float* rayData;
    float4* samp;
    unsigned short* tgrid;
    float4 *latA, *latB, *latC;
    int want;
};

// ---- dtype detector: viewdirs rows are unit-norm under the TRUE dtype ----
__global__ void detect_dtype(const void* vd, int* flag) {
    if (threadIdx.x == 0 && blockIdx.x == 0) {
        const float* f = (const float*)vd;
        const __hip_bfloat16* h = (const __hip_bfloat16*)vd;
        float sf = 0.f, sb = 0.f;
        for (int r = 0; r < 8; ++r) {
            float a = f[r*3], b = f[r*3+1], c = f[r*3+2];
            float d = (a*a + b*b + c*c) - 1.f;
            sf += d*d;
            float a2 = __bfloat162float(h[r*3]);
            float b2 = __bfloat162float(h[r*3+1]);
            float c2 = __bfloat162float(h[r*3+2]);
            float d2 = (a2*a2 + b2*b2 + c2*c2) - 1.f;
            sb += d2*d2;
        }
        bool sf_ok = (sf == sf) && (sf < 1e30f);
        bool sb_ok = (sb == sb) && (sb < 1e30f);
        int fl = 0;
        if (sb_ok && (!sf_ok || sb < sf)) fl = 1;
        *flag = fl;
    }
}

// =============== Transpose: (12, X, Y, Z) -> voxel-major [X][Y][Z][16ch] bf16 ===============
template <typename T>
__global__ __launch_bounds__(BLK)
void transpose_k(KParams<T> P) {
    if (*P.flag != P.want) return;
    const int i = blockIdx.x * BLK + threadIdx.x;
    unsigned short r[16];
    #pragma unroll
    for (int c = 0; c < 12; ++c) r[c] = f2b(ldv<T>(P.grid, c * R3I + i));
    #pragma unroll
    for (int c = 12; c < 16; ++c) r[c] = 0;
    uint4* dst = (uint4*)(P.tgrid + (size_t)i * 16);
    uint4 w0, w1;
    w0.x = (unsigned int)r[0] | ((unsigned int)r[1] << 16);
    w0.y = (unsigned int)r[2] | ((unsigned int)r[3] << 16);
    w0.z = (unsigned int)r[4] | ((unsigned int)r[5] << 16);
    w0.w = (unsigned int)r[6] | ((unsigned int)r[7] << 16);
    w1.x = (unsigned int)r[8] | ((unsigned int)r[9] << 16);
    w1.y = (unsigned int)r[10] | ((unsigned int)r[11] << 16);
    w1.z = 0; w1.w = 0;
    dst[0] = w0; dst[1] = w1;
}

// =============== Kernel 1: per-ray prep ===============
template <typename T>
__global__ __launch_bounds__(BLK)
void prep_k(KParams<T> P) {
    if (*P.flag != P.want) return;
    __shared__ float semb[BLK * 39];
    const int tid = threadIdx.x;
    const int ray = blockIdx.x * BLK + tid;
    if (ray >= NRAYS) return;
    const float ox = ldv<T>(P.rays_o, ray*3+0);
    const float oy = ldv<T>(P.rays_o, ray*3+1);
    const float oz = ldv<T>(P.rays_o, ray*3+2);
    const float dx = ldv<T>(P.rays_d, ray*3+0);
    const float dy = ldv<T>(P.rays_d, ray*3+1);
    const float dz = ldv<T>(P.rays_d, ray*3+2);
    const float vx = (dx == 0.f) ? 1e-6f : dx;
    const float vy = (dy == 0.f) ? 1e-6f : dy;
    const float vz = (dz == 0.f) ? 1e-6f : dz;
    const float rax = (1.f - ox) / vx, rbx = (-1.f - ox) / vx;
    const float ray_ = (1.f - oy) / vy, rby = (-1.f - oy) / vy;
    const float raz = (1.f - oz) / vz, rbz = (-1.f - oz) / vz;
    float tmin = fmaxf(fmaxf(fminf(rax, rbx), fminf(ray_, rby)), fminf(raz, rbz));
    float tmax = fminf(fminf(fmaxf(rax, rbx), fmaxf(ray_, rby)), fmaxf(raz, rbz));
    tmin = fminf(fmaxf(tmin, 0.05f), 3.5f);
    tmax = fminf(fmaxf(tmax, 0.05f), 3.5f);
    const bool mask_ray = (tmax <= tmin);
    const float norm_d = sqrtf(dx*dx + dy*dy + dz*dz);
    const float inv_nd = 1.f / norm_d;
    {
        float v0 = ldv<T>(P.viewdirs, ray*3+0);
        float v1 = ldv<T>(P.viewdirs, ray*3+1);
        float v2 = ldv<T>(P.viewdirs, ray*3+2);
        float* e = semb + tid*39;
        e[0] = v0; e[1] = v1; e[2] = v2;
        #pragma unroll
        for (int l = 0; l < 6; ++l) {
            float f = (float)(1 << l);
            e[3 + l*6 + 0] = __sinf(v0*f);
            e[3 + l*6 + 1] = __sinf(v1*f);
            e[3 + l*6 + 2] = __sinf(v2*f);
            e[3 + l*6 + 3] = __cosf(v0*f);
            e[3 + l*6 + 4] = __cosf(v1*f);
            e[3 + l*6 + 5] = __cosf(v2*f);
        }
    }
    float acc[16];
    #pragma unroll
    for (int j = 0; j < 16; ++j) acc[j] = ldv<T>(P.db1, j);
    const float* e = semb + tid*39;
    for (int i = 0; i < 39; ++i) {
        float xi = e[i];
        #pragma unroll
        for (int j = 0; j < 16; ++j) acc[j] = fmaf(xi, ldv<T>(P.dw1, (15+i)*16 + j), acc[j]);
    }
    float* rd = P.rayData + ray * RAYSTRIDE;
    rd[0] = ox; rd[1] = oy; rd[2] = oz;
    rd[3] = dx; rd[4] = dy; rd[5] = dz;
    rd[6] = mask_ray ? __int_as_float(0x7fc00000) : tmin;
    rd[7] = inv_nd;
    #pragma unroll
    for (int j = 0; j < 16; ++j) rd[8 + j] = acc[j];
    rd[24] = tmin * norm_d;
}

// =============== shared LDS weight layout for MLP kernels ===============
#define AW1_O 0
#define AB1_O 480
#define AW2_O 512
#define AB2_O 1536
#define AW3_O 1568
#define AB3_O 1696
#define PW1_O 1700
#define PB1_O 1892
#define PW2_O 1908
#define PB2_O 2164
#define PW3_O 2180
#define PB3_O 2436
#define DW1_O 2452   /* rows 0..14 only: 240 */
#define DW2_O 2692
#define DB2_O 2948
#define DW3_O 2964
#define DB3_O 3220
#define DW4_O 3236
#define DB4_O 3284
#define SW2_FLOATS 3287

template <typename T>
__device__ __forceinline__ void stage_w(float* dst, const T* src, int n, int tid) {
    for (int i = tid; i < n; i += BLK) dst[i] = ldv<T>(src, i);
}

template <typename T>
__device__ __forceinline__ void stage_all(float* sw, const KParams<T>& P, int tid) {
    stage_w(sw + AW1_O, P.aw1, 480, tid);
    stage_w(sw + AB1_O, P.ab1, 32, tid);
    stage_w(sw + AW2_O, P.aw2, 1024, tid);
    stage_w(sw + AB2_O, P.ab2, 32, tid);
    stage_w(sw + AW3_O, P.aw3, 128, tid);
    stage_w(sw + AB3_O, P.ab3, 4, tid);
    stage_w(sw + PW1_O, P.pw1, 192, tid);
    stage_w(sw + PB1_O, P.pb1, 16, tid);
    stage_w(sw + PW2_O, P.pw2, 256, tid);
    stage_w(sw + PB2_O, P.pb2, 16, tid);
    stage_w(sw + PW3_O, P.pw3, 256, tid);
    stage_w(sw + PB3_O, P.pb3, 16, tid);
    stage_w(sw + DW1_O, P.dw1, 240, tid);
    stage_w(sw + DW2_O, P.dw2, 256, tid);
    stage_w(sw + DB2_O, P.db2, 16, tid);
    stage_w(sw + DW3_O, P.dw3, 256, tid);
    stage_w(sw + DB3_O, P.db3, 16, tid);
    stage_w(sw + DW4_O, P.dw4, 48, tid);
    stage_w(sw + DB4_O, P.db4, 3, tid);
}

// Full MLP chain given lat[12] and position; returns float4(alpha, r, g, b)
__device__ __forceinline__ float4 mlp_chain(const float* sw, const float* rd,
                                            const float* lat, float px, float py, float pz) {
    float a1[32];
    #pragma unroll
    for (int j = 0; j < 32; ++j) a1[j] = sw[AB1_O + j];
    {
        float in3[3] = {pz, py, px};
        #pragma unroll
        for (int i = 0; i < 3; ++i) {
            float xi = in3[i];
            #pragma unroll
            for (int j = 0; j < 32; ++j) a1[j] = fmaf(xi, sw[AW1_O + i*32 + j], a1[j]);
        }
        #pragma unroll
        for (int i = 0; i < 12; ++i) {
            float xi = lat[i];
            #pragma unroll
            for (int j = 0; j < 32; ++j) a1[j] = fmaf(xi, sw[AW1_O + (3+i)*32 + j], a1[j]);
        }
    }
    #pragma unroll
    for (int j = 0; j < 32; ++j) a1[j] = fmaxf(a1[j], 0.f);
    float lg[4];
    #pragma unroll
    for (int k = 0; k < 4; ++k) lg[k] = sw[AB3_O + k];
    #pragma unroll
    for (int c = 0; c < 4; ++c) {
        float t[8];
        #pragma unroll
        for (int j = 0; j < 8; ++j) t[j] = sw[AB2_O + c*8 + j];
        #pragma unroll
        for (int i = 0; i < 32; ++i) {
            float xi = a1[i];
            #pragma unroll
            for (int j = 0; j < 8; ++j) t[j] = fmaf(xi, sw[AW2_O + i*32 + c*8 + j], t[j]);
        }
        #pragma unroll
        for (int j = 0; j < 8; ++j) {
            float tv = fmaxf(t[j], 0.f);
            #pragma unroll
            for (int k = 0; k < 4; ++k) lg[k] = fmaf(tv, sw[AW3_O + (c*8+j)*4 + k], lg[k]);
        }
    }
    float m = fmaxf(fmaxf(lg[0], lg[1]), fmaxf(lg[2], lg[3]));
    float e0 = __expf(lg[0]-m), e1 = __expf(lg[1]-m), e2 = __expf(lg[2]-m), e3 = __expf(lg[3]-m);
    float att1 = e1 / (e0 + e1 + e2 + e3);
    float p1[16];
    #pragma unroll
    for (int j = 0; j < 16; ++j) p1[j] = sw[PB1_O + j];
    #pragma unroll
    for (int i = 0; i < 12; ++i) {
        float xi = lat[i];
        #pragma unroll
        for (int j = 0; j < 16; ++j) p1[j] = fmaf(xi, sw[PW1_O + i*16 + j], p1[j]);
    }
    #pragma unroll
    for (int j = 0; j < 16; ++j) p1[j] = fmaxf(p1[j], 0.f);
    float p2[16];
    #pragma unroll
    for (int j = 0; j < 16; ++j) p2[j] = sw[PB2_O + j];
    #pragma unroll
    for (int i = 0; i < 16; ++i) {
        float xi = p1[i];
        #pragma unroll
        for (int j = 0; j < 16; ++j) p2[j] = fmaf(xi, sw[PW2_O + i*16 + j], p2[j]);
    }
    #pragma unroll
    for (int j = 0; j < 16; ++j) p2[j] = fmaxf(p2[j], 0.f);
    float po[16];
    #pragma unroll
    for (int j = 0; j < 16; ++j) po[j] = sw[PB3_O + j];
    #pragma unroll
    for (int i = 0; i < 16; ++i) {
        float xi = p2[i];
        #pragma unroll
        for (int j = 0; j < 16; ++j) po[j] = fmaf(xi, sw[PW3_O + i*16 + j], po[j]);
    }
    float d1[16];
    #pragma unroll
    for (int j = 0; j < 16; ++j) d1[j] = rd[8 + j];
    #pragma unroll
    for (int i = 0; i < 15; ++i) {
        float xi = po[i+1];
        #pragma unroll
        for (int j = 0; j < 16; ++j) d1[j] = fmaf(xi, sw[DW1_O + i*16 + j], d1[j]);
    }
    #pragma unroll
    for (int j = 0; j < 16; ++j) d1[j] = fmaxf(d1[j], 0.f);
    float d2[16];
    #pragma unroll
    for (int j = 0; j < 16; ++j) d2[j] = sw[DB2_O + j];
    #pragma unroll
    for (int i = 0; i < 16; ++i) {
        float xi = d1[i];
        #pragma unroll
        for (int j = 0; j < 16; ++j) d2[j] = fmaf(xi, sw[DW2_O + i*16 + j], d2[j]);
    }
    #pragma unroll
    for (int j = 0; j < 16; ++j) d2[j] = fmaxf(d2[j], 0.f);
    float d3[16];
    #pragma unroll
    for (int j = 0; j < 16; ++j) d3[j] = sw[DB3_O + j];
    #pragma unroll
    for (int i = 0; i < 16; ++i) {
        float xi = d2[i];
        #pragma unroll
        for (int j = 0; j < 16; ++j) d3[j] = fmaf(xi, sw[DW3_O + i*16 + j], d3[j]);
    }
    #pragma unroll
    for (int j = 0; j < 16; ++j) d3[j] = fmaxf(d3[j], 0.f);
    float rr[3];
    #pragma unroll
    for (int k = 0; k < 3; ++k) rr[k] = sw[DB4_O + k];
    #pragma unroll
    for (int i = 0; i < 16; ++i) {
        float xi = d3[i];
        #pragma unroll
        for (int k = 0; k < 3; ++k) rr[k] = fmaf(xi, sw[DW4_O + i*3 + k], rr[k]);
    }
    float dens = att1 * po[0];
    float xsh = dens + ACT_SHIFT_F;
    float sp = (xsh > 0.f) ? xsh + log1pf(__expf(-xsh)) : log1pf(__expf(xsh));
    float4 res;
    res.x = 1.f - __expf(-sp * 0.5f);
    res.y = 1.f / (1.f + __expf(-att1 * rr[0]));
    res.z = 1.f / (1.f + __expf(-att1 * rr[1]));
    res.w = 1.f / (1.f + __expf(-att1 * rr[2]));
    return res;
}

// Common per-sample position computation
__device__ __forceinline__ bool sample_pos(const float* rd, int s,
                                           float& px, float& py, float& pz) {
    const float tmin = rd[6], inv_nd = rd[7];
    const float it = fmaf(STEP_F * (float)s, inv_nd, tmin);
    px = fmaf(rd[3], it, rd[0]);
    py = fmaf(rd[4], it, rd[1]);
    pz = fmaf(rd[5], it, rd[2]);
    return (px >= -1.f) & (px <= 1.f) & (py >= -1.f) & (py <= 1.f)
         & (pz >= -1.f) & (pz <= 1.f);   // NaN tmin -> false
}

// =============== Split path kernel A: pure gather, max MLP-free occupancy ===============
template <typename T>
__global__ __launch_bounds__(BLK, 4)
void gather_k(KParams<T> P) {
    if (*P.flag != P.want) return;
    const int idx = blockIdx.x * BLK + threadIdx.x;
    const int ray = idx / NSAMP;
    const int s   = idx - ray * NSAMP;
    const float* rd = P.rayData + ray * RAYSTRIDE;
    float px, py, pz;
    if (!sample_pos(rd, s, px, py, pz)) return;
    float gx = (px + 1.f) * 79.5f;
    float gy = (py + 1.f) * 79.5f;
    float gz = (pz + 1.f) * 79.5f;
    float fx0 = floorf(gx), fy0 = floorf(gy), fz0 = floorf(gz);
    float frx = gx - fx0, fry = gy - fy0, frz = gz - fz0;
    int x0 = min(max((int)fx0, 0), RESI-1); int x1 = min(x0+1, RESI-1);
    int y0 = min(max((int)fy0, 0), RESI-1); int y1 = min(y0+1, RESI-1);
    int z0 = min(max((int)fz0, 0), RESI-1); int z1 = min(z0+1, RESI-1);
    int bx0 = x0*R2I, bx1 = x1*R2I, by0 = y0*RESI, by1 = y1*RESI;
    int vox[8] = { bx0+by0+z0, bx0+by0+z1, bx0+by1+z0, bx0+by1+z1,
                   bx1+by0+z0, bx1+by0+z1, bx1+by1+z0, bx1+by1+z1 };
    float wx0 = 1.f-frx, wy0 = 1.f-fry, wz0 = 1.f-frz;
    float wc[8] = { wx0*wy0*wz0, wx0*wy0*frz, wx0*fry*wz0, wx0*fry*frz,
                    frx*wy0*wz0, frx*wy0*frz, frx*fry*wz0, frx*fry*frz };
    const uint4* base = (const uint4*)P.tgrid;   // record i occupies base[2i], base[2i+1]
    uint4 rec[16];
    #pragma unroll
    for (int k = 0; k < 8; ++k) {
        rec[2*k]   = base[(size_t)vox[k]*2];
        rec[2*k+1] = base[(size_t)vox[k]*2 + 1];
    }
    float lat[12];
    #pragma unroll
    for (int c = 0; c < 12; ++c) lat[c] = 0.f;
    #pragma unroll
    for (int k = 0; k < 8; ++k) {
        float w = wc[k];
        uint4 a = rec[2*k], b = rec[2*k+1];
        lat[0]  = fmaf(w, lo16(a.x), lat[0]);
        lat[1]  = fmaf(w, hi16(a.x), lat[1]);
        lat[2]  = fmaf(w, lo16(a.y), lat[2]);
        lat[3]  = fmaf(w, hi16(a.y), lat[3]);
        lat[4]  = fmaf(w, lo16(a.z), lat[4]);
        lat[5]  = fmaf(w, hi16(a.z), lat[5]);
        lat[6]  = fmaf(w, lo16(a.w), lat[6]);
        lat[7]  = fmaf(w, hi16(a.w), lat[7]);
        lat[8]  = fmaf(w, lo16(b.x), lat[8]);
        lat[9]  = fmaf(w, hi16(b.x), lat[9]);
        lat[10] = fmaf(w, lo16(b.y), lat[10]);
        lat[11] = fmaf(w, hi16(b.y), lat[11]);
    }
    P.latA[idx] = make_float4(lat[0], lat[1], lat[2], lat[3]);
    P.latB[idx] = make_float4(lat[4], lat[5], lat[6], lat[7]);
    P.latC[idx] = make_float4(lat[8], lat[9], lat[10], lat[11]);
}

// =============== Split path kernel B: pure MLP, streaming lat ===============
template <typename T>
__global__ __launch_bounds__(BLK, 3)
void mlp_k(KParams<T> P) {
    if (*P.flag != P.want) return;
    __shared__ float sw[SW2_FLOATS];
    const int tid = threadIdx.x;
    stage_all(sw, P, tid);
    __syncthreads();
    const int idx = blockIdx.x * BLK + tid;
    const int ray = idx / NSAMP;
    const int s   = idx - ray * NSAMP;
    const float* rd = P.rayData + ray * RAYSTRIDE;
    float px, py, pz;
    bool inb = sample_pos(rd, s, px, py, pz);
    float4 res = make_float4(0.f, 0.f, 0.f, 0.f);
    if (inb) {
        float4 la = P.latA[idx], lb = P.latB[idx], lc = P.latC[idx];
        float lat[12] = { la.x, la.y, la.z, la.w, lb.x, lb.y, lb.z, lb.w,
                          lc.x, lc.y, lc.z, lc.w };
        res = mlp_chain(sw, rd, lat, px, py, pz);
    }
    P.samp[idx] = res;
}

// =============== Monolithic fallback (round-5): per-sample, AoS transposed grid ===============
template <typename T>
__global__ __launch_bounds__(BLK, 3)
void sample_tg_k(KParams<T> P) {
    if (*P.flag != P.want) return;
    __shared__ float sw[SW2_FLOATS];
    const int tid = threadIdx.x;
    stage_all(sw, P, tid);
    __syncthreads();
    const int idx = blockIdx.x * BLK + tid;
    const int ray = idx / NSAMP;
    const int s   = idx - ray * NSAMP;
    const float* rd = P.rayData + ray * RAYSTRIDE;
    float px, py, pz;
    bool inb = sample_pos(rd, s, px, py, pz);
    float4 res = make_float4(0.f, 0.f, 0.f, 0.f);
    if (inb) {
        float gx = (px + 1.f) * 79.5f;
        float gy = (py + 1.f) * 79.5f;
        float gz = (pz + 1.f) * 79.5f;
        float fx0 = floorf(gx), fy0 = floorf(gy), fz0 = floorf(gz);
        float frx = gx - fx0, fry = gy - fy0, frz = gz - fz0;
        int x0 = min(max((int)fx0, 0), RESI-1); int x1 = min(x0+1, RESI-1);
        int y0 = min(max((int)fy0, 0), RESI-1); int y1 = min(y0+1, RESI-1);
        int z0 = min(max((int)fz0, 0), RESI-1); int z1 = min(z0+1, RESI-1);
        int bx0 = x0*R2I, bx1 = x1*R2I, by0 = y0*RESI, by1 = y1*RESI;
        float wx0 = 1.f-frx, wy0 = 1.f-fry, wz0 = 1.f-frz;
        float wc[8] = { wx0*wy0*wz0, wx0*wy0*frz, wx0*fry*wz0, wx0*fry*frz,
                        frx*wy0*wz0, frx*wy0*frz, frx*fry*wz0, frx*fry*frz };
        int oc[8] = { (bx0+by0+z0)*16, (bx0+by0+z1)*16, (bx0+by1+z0)*16, (bx0+by1+z1)*16,
                      (bx1+by0+z0)*16, (bx1+by0+z1)*16, (bx1+by1+z0)*16, (bx1+by1+z1)*16 };
        float lat[12];
        #pragma unroll
        for (int c = 0; c < 12; ++c) lat[c] = 0.f;
        #pragma unroll
        for (int k = 0; k < 8; ++k) {
            const ushort4* p = (const ushort4*)(P.tgrid + oc[k]);
            ushort4 u0 = p[0], u1 = p[1], u2 = p[2];
            float w = wc[k];
            lat[0]  = fmaf(w, b2f(u0.x), lat[0]);
            lat[1]  = fmaf(w, b2f(u0.y), lat[1]);
            lat[2]  = fmaf(w, b2f(u0.z), lat[2]);
            lat[3]  = fmaf(w, b2f(u0.w), lat[3]);
            lat[4]  = fmaf(w, b2f(u1.x), lat[4]);
            lat[5]  = fmaf(w, b2f(u1.y), lat[5]);
            lat[6]  = fmaf(w, b2f(u1.z), lat[6]);
            lat[7]  = fmaf(w, b2f(u1.w), lat[7]);
            lat[8]  = fmaf(w, b2f(u2.x), lat[8]);
            lat[9]  = fmaf(w, b2f(u2.y), lat[9]);
            lat[10] = fmaf(w, b2f(u2.z), lat[10]);
            lat[11] = fmaf(w, b2f(u2.w), lat[11]);
        }
        res = mlp_chain(sw, rd, lat, px, py, pz);
    }
    P.samp[idx] = res;
}

// =============== Small-ws fallback: scattered gather from original grid ===============
template <typename T>
__global__ __launch_bounds__(BLK, 3)
void sample_k(KParams<T> P) {
    if (*P.flag != P.want) return;
    __shared__ float sw[SW2_FLOATS];
    const int tid = threadIdx.x;
    stage_all(sw, P, tid);
    __syncthreads();
    const int idx = blockIdx.x * BLK + tid;
    const int ray = idx / NSAMP;
    const int s   = idx - ray * NSAMP;
    const float* rd = P.rayData + ray * RAYSTRIDE;
    float px, py, pz;
    bool inb = sample_pos(rd, s, px, py, pz);
    float4 res = make_float4(0.f, 0.f, 0.f, 0.f);
    if (inb) {
        float gx = (px + 1.f) * 79.5f;
        float gy = (py + 1.f) * 79.5f;
        float gz = (pz + 1.f) * 79.5f;
        float fx0 = floorf(gx), fy0 = floorf(gy), fz0 = floorf(gz);
        float frx = gx - fx0, fry = gy - fy0, frz = gz - fz0;
        int x0 = min(max((int)fx0, 0), RESI-1); int x1 = min(x0+1, RESI-1);
        int y0 = min(max((int)fy0, 0), RESI-1); int y1 = min(y0+1, RESI-1);
        int z0 = min(max((int)fz0, 0), RESI-1); int z1 = min(z0+1, RESI-1);
        int bx0 = x0*R2I, bx1 = x1*R2I, by0 = y0*RESI, by1 = y1*RESI;
        int o000 = bx0+by0+z0, o001 = bx0+by0+z1, o010 = bx0+by1+z0, o011 = bx0+by1+z1;
        int o100 = bx1+by0+z0, o101 = bx1+by0+z1, o110 = bx1+by1+z0, o111 = bx1+by1+z1;
        float wx0 = 1.f-frx, wy0 = 1.f-fry, wz0 = 1.f-frz;
        float w000 = wx0*wy0*wz0, w001 = wx0*wy0*frz, w010 = wx0*fry*wz0, w011 = wx0*fry*frz;
        float w100 = frx*wy0*wz0, w101 = frx*wy0*frz, w110 = frx*fry*wz0, w111 = frx*fry*frz;
        float lat[12];
        #pragma unroll
        for (int c = 0; c < 12; ++c) {
            const T* g = P.grid + c*R3I;
            lat[c] = w000*ldv<T>(g,o000) + w001*ldv<T>(g,o001)
                   + w010*ldv<T>(g,o010) + w011*ldv<T>(g,o011)
                   + w100*ldv<T>(g,o100) + w101*ldv<T>(g,o101)
                   + w110*ldv<T>(g,o110) + w111*ldv<T>(g,o111);
        }
        res = mlp_chain(sw, rd, lat, px, py, pz);
    }
    P.samp[idx] = res;
}

// =============== Kernel 3: per-ray composite (one wave per ray) ===============
template <typename T>
__global__ __launch_bounds__(64)
void composite_k(KParams<T> P) {
    if (*P.flag != P.want) return;
    const int ray = blockIdx.x;
    const int lane = threadIdx.x;
    const float base_depth = P.rayData[ray * RAYSTRIDE + 24];
    const float4* sp = P.samp + ray * NSAMP;
    float lp = 1.f, cr = 0.f, cg = 0.f, cb = 0.f, cd = 0.f, ca = 0.f;
    #pragma unroll
    for (int k = 0; k < 9; ++k) {
        int s = lane * 9 + k;
        if (s < NSAMP) {
            float4 sm = sp[s];
            float w = sm.x * lp;
            cr += w * sm.y;
            cg += w * sm.z;
            cb += w * sm.w;
            cd += w * (base_depth + STEP_F * (float)s);
            ca += w;
            lp *= fmaxf(1.f - sm.x, 1e-10f);
        }
    }
    float pincl = lp;
    #pragma unroll
    for (int off = 1; off < 64; off <<= 1) {
        float v = __shfl_up(pincl, off, 64);
        if (lane >= off) pincl *= v;
    }
    float Tf = __shfl(pincl, 63, 64);
    float excl = __shfl_up(pincl, 1, 64);
    if (lane == 0) excl = 1.f;
    cr *= excl; cg *= excl; cb *= excl; cd *= excl; ca *= excl;
    #pragma unroll
    for (int off = 32; off > 0; off >>= 1) {
        cr += __shfl_down(cr, off, 64);
        cg += __shfl_down(cg, off, 64);
        cb += __shfl_down(cb, off, 64);
        cd += __shfl_down(cd, off, 64);
        ca += __shfl_down(ca, off, 64);
    }
    if (lane == 0) {
        float depth_m = cd + Tf * 3.5f;
        T* o = P.out + ray*6;
        o[0] = cvt_out<T>(cr + Tf);
        o[1] = cvt_out<T>(cg + Tf);
        o[2] = cvt_out<T>(cb + Tf);
        o[3] = cvt_out<T>(depth_m);
        o[4] = cvt_out<T>(1.f / depth_m);
        o[5] = cvt_out<T>(ca);
    }
}

template <typename T>
static void fill_params(KParams<T>& P, void* const* d_in, void* d_out, void* d_ws, int want) {
    P.rays_o   = (const T*)d_in[0];
    P.rays_d   = (const T*)d_in[1];
    P.viewdirs = (const T*)d_in[2];
    P.grid     = (const T*)d_in[3];
    P.aw1 = (const T*)d_in[4];  P.ab1 = (const T*)d_in[5];
    P.aw2 = (const T*)d_in[6];  P.ab2 = (const T*)d_in[7];
    P.aw3 = (const T*)d_in[8];  P.ab3 = (const T*)d_in[9];
    P.pw1 = (const T*)d_in[10]; P.pb1 = (const T*)d_in[11];
    P.pw2 = (const T*)d_in[12]; P.pb2 = (const T*)d_in[13];
    P.pw3 = (const T*)d_in[14]; P.pb3 = (const T*)d_in[15];
    P.dw1 = (const T*)d_in[16]; P.db1 = (const T*)d_in[17];
    P.dw2 = (const T*)d_in[18]; P.db2 = (const T*)d_in[19];
    P.dw3 = (const T*)d_in[20]; P.db3 = (const T*)d_in[21];
    P.dw4 = (const T*)d_in[22]; P.db4 = (const T*)d_in[23];
    P.out = (T*)d_out;
    P.flag = (const int*)d_ws;
    P.rayData = (float*)((char*)d_ws + RAYDATA_OFF);
    P.samp = (float4*)((char*)d_ws + SAMP_OFF);
    P.tgrid = (unsigned short*)((char*)d_ws + TG_OFF);
    P.latA = (float4*)((char*)d_ws + LAT_OFF);
    P.latB = (float4*)((char*)d_ws + LAT_OFF + (size_t)NTOT * 16);
    P.latC = (float4*)((char*)d_ws + LAT_OFF + (size_t)NTOT * 32);
    P.want = want;
}

extern "C" void kernel_launch(void* const* d_in, const int* in_sizes, int n_in,
                              void* d_out, int out_size, void* d_ws, size_t ws_size,
                              hipStream_t stream) {
    int* flag = (int*)d_ws;
    hipLaunchKernelGGL(detect_dtype, dim3(1), dim3(64), 0, stream, d_in[2], flag);

    KParams<float> Pf;
    fill_params<float>(Pf, d_in, d_out, d_ws, 0);
    KParams<__hip_bfloat16> Pb;
    fill_params<__hip_bfloat16>(Pb, d_in, d_out, d_ws, 1);

    hipLaunchKernelGGL(prep_k<float>, dim3((NRAYS + BLK - 1)/BLK), dim3(BLK), 0, stream, Pf);
    hipLaunchKernelGGL(prep_k<__hip_bfloat16>, dim3((NRAYS + BLK - 1)/BLK), dim3(BLK), 0, stream, Pb);

    if (ws_size >= WS_SPLIT) {
        hipLaunchKernelGGL(transpose_k<float>, dim3(TG_BLOCKS), dim3(BLK), 0, stream, Pf);
        hipLaunchKernelGGL(transpose_k<__hip_bfloat16>, dim3(TG_BLOCKS), dim3(BLK), 0, stream, Pb);
        hipLaunchKernelGGL(gather_k<float>, dim3(SAMP_BLOCKS), dim3(BLK), 0, stream, Pf);
        hipLaunchKernelGGL(gather_k<__hip_bfloat16>, dim3(SAMP_BLOCKS), dim3(BLK), 0, stream, Pb);
        hipLaunchKernelGGL(mlp_k<float>, dim3(SAMP_BLOCKS), dim3(BLK), 0, stream, Pf);
        hipLaunchKernelGGL(mlp_k<__hip_bfloat16>, dim3(SAMP_BLOCKS), dim3(BLK), 0, stream, Pb);
    } else if (ws_size >= WS_BIG) {
        hipLaunchKernelGGL(transpose_k<float>, dim3(TG_BLOCKS), dim3(BLK), 0, stream, Pf);
        hipLaunchKernelGGL(transpose_k<__hip_bfloat16>, dim3(TG_BLOCKS), dim3(BLK), 0, stream, Pb);
        hipLaunchKernelGGL(sample_tg_k<float>, dim3(SAMP_BLOCKS), dim3(BLK), 0, stream, Pf);
        hipLaunchKernelGGL(sample_tg_k<__hip_bfloat16>, dim3(SAMP_BLOCKS), dim3(BLK), 0, stream, Pb);
    } else {
        hipLaunchKernelGGL(sample_k<float>, dim3(SAMP_BLOCKS), dim3(BLK), 0, stream, Pf);
        hipLaunchKernelGGL(sample_k<__hip_bfloat16>, dim3(SAMP_BLOCKS), dim3(BLK), 0, stream, Pb);
    }
    hipLaunchKernelGGL(composite_k<float>, dim3(NRAYS), dim3(64), 0, stream, Pf);
    hipLaunchKernelGGL(composite_k<__hip_bfloat16>, dim3(NRAYS), dim3(64), 0, stream, Pb);
}